// Round 7
// baseline (207.591 us; speedup 1.0000x reference)
//
#include <hip/hip_runtime.h>

constexpr int BLK = 256;  // threads == elements per block

// Compiler-proof IEEE f32 rn ops (inline asm: no fusion/reassociation
// beyond what is written).
__device__ __forceinline__ float mul_rn(float a, float b) {
    float r; asm("v_mul_f32 %0, %1, %2" : "=v"(r) : "v"(a), "v"(b)); return r;
}
__device__ __forceinline__ float add_rn(float a, float b) {
    float r; asm("v_add_f32 %0, %1, %2" : "=v"(r) : "v"(a), "v"(b)); return r;
}
__device__ __forceinline__ float sub_rn(float a, float b) {
    float r; asm("v_sub_f32 %0, %1, %2" : "=v"(r) : "v"(a), "v"(b)); return r;
}
__device__ __forceinline__ float fma_rn(float a, float b, float c) {
    float r; asm("v_fma_f32 %0, %1, %2, %3"
                 : "=v"(r) : "v"(a), "v"(b), "v"(c)); return r;
}

// Ascending FMA chain from zero — the evaluation shared by an XLA-lowered
// dot loop (acc=0; acc=fma(a_j,b_j,acc)) and BLAS 3x3 microkernels:
//   fma(a2,b2, fma(a1,b1, rn(a0*b0)))      [fma(a0,b0,0) == rn(a0*b0)]
// R5 (strict asc) and R6 (strict desc) both gave bit-identical absmax 4.53
// => plain-rn in any order mismatches the np ref's ca bits at the razor
// elements (1+ca ~ 1e-7, ~1 ulp of tr -> ~4.5 output). R1/3/4's compiler
// contraction fused the LEFT mul: fma(a2,b2, fma(a0,b0, rn(a1*b1))) — a
// different, also-failing chain. This is the remaining canonical candidate.
__device__ __forceinline__ float dot3_fma_asc(float a0, float a1, float a2,
                                              float b0, float b1, float b2) {
    return fma_rn(a2, b2, fma_rn(a1, b1, mul_rn(a0, b0)));
}

__global__ __launch_bounds__(BLK) void so3_nll_kernel(
    const float* __restrict__ C_est,
    const float* __restrict__ C_tgt,
    const float* __restrict__ Rinv,
    float* __restrict__ out,
    int B)
{
    __shared__ float sE[BLK * 9];
    __shared__ float sT[BLK * 9];
    __shared__ float sR[BLK * 9];

    const int tid  = threadIdx.x;
    const int b0   = blockIdx.x * BLK;
    const int nrem = min(BLK, B - b0);   // elements handled by this block
    const int nflt = nrem * 9;           // floats per input array
    const int nvec = nflt >> 2;          // full float4 chunks

    // Coalesced global -> LDS staging. Block base byte offset = b0*36,
    // b0 multiple of 256 -> offset multiple of 9216 (16B aligned).
    const float4* gE = reinterpret_cast<const float4*>(C_est + (size_t)b0 * 9);
    const float4* gT = reinterpret_cast<const float4*>(C_tgt + (size_t)b0 * 9);
    const float4* gR = reinterpret_cast<const float4*>(Rinv  + (size_t)b0 * 9);

    for (int i = tid; i < nvec; i += BLK) {
        float4 e = gE[i];
        float4 t = gT[i];
        float4 r = gR[i];
        *reinterpret_cast<float4*>(&sE[i * 4]) = e;
        *reinterpret_cast<float4*>(&sT[i * 4]) = t;
        *reinterpret_cast<float4*>(&sR[i * 4]) = r;
    }
    // Scalar tail (nflt % 4 floats) — only possible in the last block.
    for (int i = (nvec << 2) + tid; i < nflt; i += BLK) {
        sE[i] = C_est[(size_t)b0 * 9 + i];
        sT[i] = C_tgt[(size_t)b0 * 9 + i];
        sR[i] = Rinv [(size_t)b0 * 9 + i];
    }
    __syncthreads();

    if (tid < nrem) {
        const float* E = &sE[tid * 9];   // stride 9 (odd) -> bank-conflict-free
        const float* T = &sT[tid * 9];
        const float* R = &sR[tid * 9];

        // ---- chaotic chain: must match the np ref's f32 rounding ----
        float d00 = dot3_fma_asc(E[0],E[1],E[2], T[0],T[1],T[2]);
        float d11 = dot3_fma_asc(E[3],E[4],E[5], T[3],T[4],T[5]);
        float d22 = dot3_fma_asc(E[6],E[7],E[8], T[6],T[7],T[8]);

        float tr = add_rn(add_rn(d00, d11), d22);    // (d00+d11)+d22
        float ca = 0.5f * sub_rn(tr, 1.0f);          // *0.5 exact
        constexpr float HI = 1.0f - 1e-7f;           // 0x3F7FFFFE == np bound
        ca = fminf(fmaxf(ca, -HI), HI);
        float angle = acosf(ca);
        float sa    = sinf(angle);
        // clamp => angle >= ~4.9e-4 > 1e-6: reference Taylor branch is dead
        float coef = (0.5f * angle) / sa;

        // ---- vee path: same chain for consistency ----
        float d01 = dot3_fma_asc(E[0],E[1],E[2], T[3],T[4],T[5]);
        float d02 = dot3_fma_asc(E[0],E[1],E[2], T[6],T[7],T[8]);
        float d10 = dot3_fma_asc(E[3],E[4],E[5], T[0],T[1],T[2]);
        float d12 = dot3_fma_asc(E[3],E[4],E[5], T[6],T[7],T[8]);
        float d20 = dot3_fma_asc(E[6],E[7],E[8], T[0],T[1],T[2]);
        float d21 = dot3_fma_asc(E[6],E[7],E[8], T[3],T[4],T[5]);

        float r0 = coef * sub_rn(d21, d12);
        float r1 = coef * sub_rn(d02, d20);
        float r2 = coef * sub_rn(d10, d01);

        // ---- well-conditioned tail: plain f32 ----
        float w = 0.5f * (r0 * ((R[0]*r0 + R[1]*r1) + R[2]*r2) +
                          r1 * ((R[3]*r0 + R[4]*r1) + R[5]*r2) +
                          r2 * ((R[6]*r0 + R[7]*r1) + R[8]*r2));

        float det = R[0] * (R[4]*R[8] - R[5]*R[7])
                  - R[1] * (R[3]*R[8] - R[5]*R[6])
                  + R[2] * (R[3]*R[7] - R[4]*R[6]);

        out[b0 + tid] = w - 0.5f * logf(det);
    }
}

extern "C" void kernel_launch(void* const* d_in, const int* in_sizes, int n_in,
                              void* d_out, int out_size, void* d_ws, size_t ws_size,
                              hipStream_t stream) {
    const float* C_est = (const float*)d_in[0];
    const float* C_tgt = (const float*)d_in[1];
    const float* Rinv  = (const float*)d_in[2];
    float* out = (float*)d_out;

    const int B = in_sizes[0] / 9;
    const int blocks = (B + BLK - 1) / BLK;
    so3_nll_kernel<<<blocks, BLK, 0, stream>>>(C_est, C_tgt, Rinv, out, B);
}